// Round 1
// baseline (553.589 us; speedup 1.0000x reference)
//
#include <hip/hip_runtime.h>

// WaveNet single-output inference on MI355X.
// Key insight: reference returns only z[:, 0, -1:], and f1/f2 are 1x1 convs,
// so only skip_sum[:, :, 8190] is needed. Dilated convs are non-causal
// (pad d/2 both sides, taps t-d/2 and t+d/2), so the needed window of the
// residual stream is only [6143, 8191] (2049 positions), shrinking per layer.

#define BASE   6143
#define NSLOT  2049      // slots 0..2048  <->  t in [6143, 8191]
#define TLAST  8190      // last output position of every layer (length 8191)
#define POS    16        // positions per block chunk
#define BATCH  32

// ---------------------------------------------------------------- input conv
__global__ __launch_bounds__(512) void wn_in_conv(
    const float* __restrict__ x, const float* __restrict__ w_,
    const float* __restrict__ b_, float* __restrict__ h0,
    float* __restrict__ skip_acc)
{
    __shared__ float xs[POS][16];
    const int tid = threadIdx.x;
    const int b   = blockIdx.y;
    const int p   = tid >> 5, c = tid & 31;
    const int t   = BASE + (blockIdx.x * POS + p);
    const bool valid = (t <= BASE + NSLOT - 1);   // t <= 8191

    if (blockIdx.x == 0 && tid < 32) skip_acc[b * 32 + tid] = 0.f;

    float wreg[16];
    #pragma unroll
    for (int f = 0; f < 16; ++f) wreg[f] = w_[c * 16 + f];

    if (c < 16) xs[p][c] = valid ? x[((size_t)b * 8192 + t) * 16 + c] : 0.f;
    __syncthreads();

    float acc = b_[c];
    #pragma unroll
    for (int f = 0; f < 16; ++f) acc += wreg[f] * xs[p][f];

    if (valid)
        h0[((size_t)b * NSLOT + (t - BASE)) * 32 + c] = acc;
}

// ---------------------------------------------------------------- one layer
// y[t] = W0 * h[tA] + W1 * h[tB]  (tB beyond TLAST -> zero padding)
//   l==0 (d=1, no pad):  tA = t,      tB = t+1   (h0 valid through 8191)
//   l>=1 (d even)     :  tA = t-d/2,  tB = t+d/2 (valid through 8190)
// g = tanh(filt)*sigmoid(gate);  hout[t] = res_w*g + h[resid];  skip only at TLAST.
__global__ __launch_bounds__(512) void wn_layer(
    const float* __restrict__ hin, float* __restrict__ hout,
    const float* __restrict__ dw, const float* __restrict__ db,
    const float* __restrict__ rw, const float* __restrict__ rb,
    const float* __restrict__ sw, const float* __restrict__ sb,
    float* __restrict__ skip_acc,
    int half, int first, int outStart, int outCount)
{
    __shared__ float wg  [64][65];   // [oc'][2*ic+tap], pad 65 -> conflict-free
    __shared__ float wres[32][33];
    __shared__ float wskip[32][33];
    __shared__ float hA  [POS][32];
    __shared__ float hB  [POS][32];
    __shared__ float hRs [POS][32];
    __shared__ float gbuf[POS][32];

    const int tid = threadIdx.x;
    const int b   = blockIdx.y;
    const int p   = tid >> 5, c = tid & 31;

    for (int i = tid; i < 4096; i += 512) wg[i >> 6][i & 63] = dw[i];
    for (int i = tid; i < 1024; i += 512) {
        wres [i >> 5][i & 31] = rw[i];
        wskip[i >> 5][i & 31] = sw[i];
    }

    const float gbias = db[c], fbias = db[c + 32];
    const float rbias = rb[c], sbias = sb[c];
    const float* hb = hin  + (size_t)b * NSLOT * 32;
    float*       ho = hout + (size_t)b * NSLOT * 32;

    const int nChunk = (outCount + POS - 1) / POS;
    for (int chunk = blockIdx.x; chunk < nChunk; chunk += gridDim.x) {
        const int  t     = outStart + chunk * POS + p;
        const bool valid = (t <= TLAST);

        __syncthreads();   // previous-iter LDS reads done (also covers weights, iter 0)
        if (valid) {
            const int tA = first ? t : (t - half);
            hA[p][c] = hb[(tA - BASE) * 32 + c];
            const int tB   = first ? (t + 1) : (t + half);
            const int rmax = first ? (BASE + NSLOT - 1) : TLAST;
            hB[p][c] = (tB <= rmax) ? hb[(tB - BASE) * 32 + c] : 0.f;
            const int tR = first ? (t + 1) : t;      // residual alignment
            hRs[p][c] = hb[(tR - BASE) * 32 + c];
        }
        __syncthreads();

        float g = 0.f;
        if (valid) {
            float gate = gbias, filt = fbias;
            #pragma unroll
            for (int ic = 0; ic < 32; ++ic) {
                const float a = hA[p][ic], r = hB[p][ic];
                gate += wg[c     ][2 * ic] * a + wg[c     ][2 * ic + 1] * r;
                filt += wg[c + 32][2 * ic] * a + wg[c + 32][2 * ic + 1] * r;
            }
            g = tanhf(filt) / (1.f + expf(-gate));   // tanh(filt)*sigmoid(gate)
        }
        gbuf[p][c] = g;
        __syncthreads();

        if (valid) {
            float o = rbias;
            #pragma unroll
            for (int ic = 0; ic < 32; ++ic) o += wres[c][ic] * gbuf[p][ic];
            ho[(t - BASE) * 32 + c] = o + hRs[p][c];

            if (t == TLAST) {
                float s = sbias;
                #pragma unroll
                for (int ic = 0; ic < 32; ++ic) s += wskip[c][ic] * gbuf[p][ic];
                skip_acc[b * 32 + c] += s;
            }
        }
    }
}

// ---------------------------------------------------------------- head
// out[b] = f2( relu( f1( relu(skip_sum[b]) ) ) )   (all 1x1)
__global__ __launch_bounds__(1024) void wn_head(
    const float* __restrict__ skip_acc,
    const float* __restrict__ f1w, const float* __restrict__ f1b,
    const float* __restrict__ f2w, const float* __restrict__ f2b,
    float* __restrict__ out)
{
    __shared__ float z1s[32][33];
    const int tid = threadIdx.x;
    const int b = tid >> 5, c = tid & 31;

    float z = f1b[c];
    #pragma unroll
    for (int ic = 0; ic < 32; ++ic)
        z += f1w[c * 32 + ic] * fmaxf(skip_acc[b * 32 + ic], 0.f);
    z1s[b][c] = fmaxf(z, 0.f);
    __syncthreads();

    if (c == 0) {
        float o = f2b[0];
        #pragma unroll
        for (int ic = 0; ic < 32; ++ic) o += f2w[ic] * z1s[b][ic];
        out[b] = o;
    }
}

// ---------------------------------------------------------------- launch
extern "C" void kernel_launch(void* const* d_in, const int* in_sizes, int n_in,
                              void* d_out, int out_size, void* d_ws, size_t ws_size,
                              hipStream_t stream)
{
    const float* x      = (const float*)d_in[0];
    const float* in_w   = (const float*)d_in[1];
    const float* in_b   = (const float*)d_in[2];
    const float* dil_w  = (const float*)d_in[3];
    const float* dil_b  = (const float*)d_in[4];
    const float* skip_w = (const float*)d_in[5];
    const float* skip_b = (const float*)d_in[6];
    const float* res_w  = (const float*)d_in[7];
    const float* res_b  = (const float*)d_in[8];
    const float* f1_w   = (const float*)d_in[9];
    const float* f1_b   = (const float*)d_in[10];
    const float* f2_w   = (const float*)d_in[11];
    const float* f2_b   = (const float*)d_in[12];

    float* ws = (float*)d_ws;
    const size_t HB = (size_t)BATCH * NSLOT * 32;     // one h buffer (floats)
    float* hbuf[2]  = { ws, ws + HB };
    float* skip_acc = ws + 2 * HB;                    // [32][32]
    // total ws need: (2*HB + 1024)*4 B ~= 16.8 MB

    static const int dils[12]   = {1, 2, 4, 8, 16, 32, 64, 128, 256, 512, 1024, 2048};
    static const int starts[12] = {6143, 6144, 6146, 6150, 6158, 6174,
                                   6206, 6270, 6398, 6654, 7166, 8190};

    wn_in_conv<<<dim3((NSLOT + POS - 1) / POS, BATCH), dim3(512), 0, stream>>>(
        x, in_w, in_b, hbuf[0], skip_acc);

    for (int l = 0; l < 12; ++l) {
        const int cnt    = TLAST - starts[l] + 1;
        const int nChunk = (cnt + POS - 1) / POS;
        const int gx     = nChunk < 32 ? nChunk : 32;
        wn_layer<<<dim3(gx, BATCH), dim3(512), 0, stream>>>(
            hbuf[l & 1], hbuf[(l + 1) & 1],
            dil_w + (size_t)l * 64 * 32 * 2, dil_b + l * 64,
            res_w + (size_t)l * 32 * 32,     res_b + l * 32,
            skip_w + (size_t)l * 32 * 32,    skip_b + l * 32,
            skip_acc, dils[l] / 2, (l == 0) ? 1 : 0, starts[l], cnt);
    }

    wn_head<<<dim3(1), dim3(1024), 0, stream>>>(
        skip_acc, f1_w, f1_b, f2_w, f2_b, (float*)d_out);
}

// Round 2
// 354.705 us; speedup vs baseline: 1.5607x; 1.5607x over previous
//
#include <hip/hip_runtime.h>

// WaveNet single-output inference on MI355X.
// Only skip_sum[:, :, 8190] matters => back-propagated windows: residual
// stream needed only on t in [6143, 8191] (2049 slots), shrinking per layer.
// Layer l window start: starts[l]; all layers end at t=8190.

#define BASE   6143
#define NSLOT  2049      // slots 0..2048  <->  t in [6143, 8191]
#define TLAST  8190
#define POSC   32        // positions per block
#define BATCH  32

// ---------------------------------------------------------------- input conv
__global__ __launch_bounds__(512) void wn_in_conv(
    const float* __restrict__ x, const float* __restrict__ w_,
    const float* __restrict__ b_, float* __restrict__ h0,
    float* __restrict__ skip_acc)
{
    __shared__ float xs[16][16];
    const int tid = threadIdx.x;
    const int b   = blockIdx.y;
    const int p   = tid >> 5, c = tid & 31;
    const int t   = BASE + (blockIdx.x * 16 + p);
    const bool valid = (t <= BASE + NSLOT - 1);

    if (blockIdx.x == 0 && tid < 32) skip_acc[b * 32 + tid] = 0.f;

    float wreg[16];
    #pragma unroll
    for (int f = 0; f < 16; ++f) wreg[f] = w_[c * 16 + f];

    if (c < 16) xs[p][c] = valid ? x[((size_t)b * 8192 + t) * 16 + c] : 0.f;
    __syncthreads();

    float acc = b_[c];
    #pragma unroll
    for (int f = 0; f < 16; ++f) acc += wreg[f] * xs[p][f];

    if (valid)
        h0[((size_t)b * NSLOT + (t - BASE)) * 32 + c] = acc;
}

// ---------------------------------------------------------------- one layer
// Semantics identical to the round-1 passing kernel:
//   l==0 (first): tA=t, tB=t+1 (rmax 8191), tR=t+1
//   l>=1:         tA=t-half, tB=t+half (0 beyond 8190), tR=t
__global__ __launch_bounds__(256, 4) void wn_layer(
    const float* __restrict__ hin, float* __restrict__ hout,
    const float* __restrict__ dw, const float* __restrict__ db,
    const float* __restrict__ rw, const float* __restrict__ rb,
    const float* __restrict__ sw, const float* __restrict__ sb,
    float* __restrict__ skip_acc,
    int half, int first, int outStart)
{
    // packed gate/filt weights: row c, entry 4*ic+{wg0,wg1,wf0,wf1}
    __shared__ __align__(16) float wPK[32 * 132];   // stride 132: uniform banks
    __shared__ __align__(16) float sA [32 * 36];    // [ch][pos], stride 36
    __shared__ __align__(16) float sB [32 * 36];
    __shared__ __align__(16) float sG [32 * 36];
    __shared__ float wres [32 * 33];
    __shared__ float wskip[32 * 33];

    const int tid = threadIdx.x;
    const int b   = blockIdx.y;
    const int t0  = outStart + blockIdx.x * POSC;
    const float* hb = hin  + (size_t)b * NSLOT * 32;
    float*       ho = hout + (size_t)b * NSLOT * 32;

    // ---- stage weights
    for (int i = tid; i < 4096; i += 256) {
        const int c = i >> 7, k = i & 127;
        const int ic = k >> 2, s = k & 3;
        wPK[c * 132 + k] = dw[(c + (s >> 1) * 32) * 64 + 2 * ic + (s & 1)];
    }
    for (int i = tid; i < 1024; i += 256) {
        wres [(i >> 5) * 33 + (i & 31)] = rw[i];
        wskip[(i >> 5) * 33 + (i & 31)] = sw[i];
    }

    // ---- stage h windows, transposed [ch][pos]
    {
        const int pos = tid >> 3;              // 0..31
        const int c4  = (tid & 7) * 4;
        const int aS  = first ? t0 : (t0 - half);
        const int bS  = first ? (t0 + 1) : (t0 + half);
        const int rmaxSlot = (first ? (BASE + NSLOT - 1) : TLAST) - BASE;

        int sa = aS - BASE + pos;
        if (sa > NSLOT - 1) sa = NSLOT - 1;                 // tail clamp (discarded)
        const float4 va = *(const float4*)&hb[(size_t)sa * 32 + c4];

        const int sbs = bS - BASE + pos;
        float4 vb = make_float4(0.f, 0.f, 0.f, 0.f);
        if (sbs <= rmaxSlot) vb = *(const float4*)&hb[(size_t)sbs * 32 + c4];

        sA[(c4 + 0) * 36 + pos] = va.x;  sA[(c4 + 1) * 36 + pos] = va.y;
        sA[(c4 + 2) * 36 + pos] = va.z;  sA[(c4 + 3) * 36 + pos] = va.w;
        sB[(c4 + 0) * 36 + pos] = vb.x;  sB[(c4 + 1) * 36 + pos] = vb.y;
        sB[(c4 + 2) * 36 + pos] = vb.z;  sB[(c4 + 3) * 36 + pos] = vb.w;
    }

    const int tp = tid >> 5;       // 0..7  (4 positions each)
    const int c  = tid & 31;
    const int base_t = t0 + tp * 4;

    // residual taps straight from global (L2/L3-resident), issued pre-barrier
    float rv[4];
    #pragma unroll
    for (int j = 0; j < 4; ++j) {
        const int t  = base_t + j;
        int slotR = (first ? t + 1 : t) - BASE;
        if (slotR > NSLOT - 1) slotR = NSLOT - 1;
        rv[j] = hb[(size_t)slotR * 32 + c];
    }

    __syncthreads();

    // ---- gate/filt: 64x64 matmul slice, 4 positions per thread
    float gg[4], ff[4];
    {
        const float gb = db[c], fb = db[c + 32];
        #pragma unroll
        for (int j = 0; j < 4; ++j) { gg[j] = gb; ff[j] = fb; }
    }
    const float* wrow = &wPK[c * 132];
    #pragma unroll
    for (int ic = 0; ic < 32; ++ic) {
        const float4 w  = *(const float4*)&wrow[4 * ic];
        const float4 a  = *(const float4*)&sA[ic * 36 + tp * 4];
        const float4 bb = *(const float4*)&sB[ic * 36 + tp * 4];
        gg[0] += w.x * a.x + w.y * bb.x;  ff[0] += w.z * a.x + w.w * bb.x;
        gg[1] += w.x * a.y + w.y * bb.y;  ff[1] += w.z * a.y + w.w * bb.y;
        gg[2] += w.x * a.z + w.y * bb.z;  ff[2] += w.z * a.z + w.w * bb.z;
        gg[3] += w.x * a.w + w.y * bb.w;  ff[3] += w.z * a.w + w.w * bb.w;
    }

    // activation: tanh(f)*sigmoid(g)
    float4 gvv;
    {
        float gv[4];
        #pragma unroll
        for (int j = 0; j < 4; ++j) {
            const float sg = 1.f / (1.f + __expf(-gg[j]));
            const float th = 2.f / (1.f + __expf(-2.f * ff[j])) - 1.f;
            gv[j] = th * sg;
        }
        gvv = make_float4(gv[0], gv[1], gv[2], gv[3]);
    }
    *(float4*)&sG[c * 36 + tp * 4] = gvv;

    __syncthreads();

    // ---- res conv + residual add + store
    float rr[4];
    {
        const float rbias = rb[c];
        #pragma unroll
        for (int j = 0; j < 4; ++j) rr[j] = rbias;
    }
    #pragma unroll
    for (int ic = 0; ic < 32; ++ic) {
        const float w  = wres[c * 33 + ic];
        const float4 g = *(const float4*)&sG[ic * 36 + tp * 4];
        rr[0] += w * g.x;  rr[1] += w * g.y;
        rr[2] += w * g.z;  rr[3] += w * g.w;
    }
    #pragma unroll
    for (int j = 0; j < 4; ++j) {
        const int t = base_t + j;
        if (t <= TLAST) ho[(size_t)(t - BASE) * 32 + c] = rr[j] + rv[j];
    }

    // ---- skip conv, only at t == TLAST (one block per (layer, batch))
    if (t0 <= TLAST && TLAST < t0 + POSC && tid < 32) {
        const int pL = TLAST - t0;
        float s = sb[tid];
        #pragma unroll
        for (int ic = 0; ic < 32; ++ic)
            s += wskip[tid * 33 + ic] * sG[ic * 36 + pL];
        skip_acc[b * 32 + tid] += s;
    }
}

// ---------------------------------------------------------------- head
__global__ __launch_bounds__(1024) void wn_head(
    const float* __restrict__ skip_acc,
    const float* __restrict__ f1w, const float* __restrict__ f1b,
    const float* __restrict__ f2w, const float* __restrict__ f2b,
    float* __restrict__ out)
{
    __shared__ float z1s[32][33];
    const int tid = threadIdx.x;
    const int b = tid >> 5, c = tid & 31;

    float z = f1b[c];
    #pragma unroll
    for (int ic = 0; ic < 32; ++ic)
        z += f1w[c * 32 + ic] * fmaxf(skip_acc[b * 32 + ic], 0.f);
    z1s[b][c] = fmaxf(z, 0.f);
    __syncthreads();

    if (c == 0) {
        float o = f2b[0];
        #pragma unroll
        for (int ic = 0; ic < 32; ++ic) o += f2w[ic] * z1s[b][ic];
        out[b] = o;
    }
}

// ---------------------------------------------------------------- launch
extern "C" void kernel_launch(void* const* d_in, const int* in_sizes, int n_in,
                              void* d_out, int out_size, void* d_ws, size_t ws_size,
                              hipStream_t stream)
{
    const float* x      = (const float*)d_in[0];
    const float* in_w   = (const float*)d_in[1];
    const float* in_b   = (const float*)d_in[2];
    const float* dil_w  = (const float*)d_in[3];
    const float* dil_b  = (const float*)d_in[4];
    const float* skip_w = (const float*)d_in[5];
    const float* skip_b = (const float*)d_in[6];
    const float* res_w  = (const float*)d_in[7];
    const float* res_b  = (const float*)d_in[8];
    const float* f1_w   = (const float*)d_in[9];
    const float* f1_b   = (const float*)d_in[10];
    const float* f2_w   = (const float*)d_in[11];
    const float* f2_b   = (const float*)d_in[12];

    float* ws = (float*)d_ws;
    const size_t HB = (size_t)BATCH * NSLOT * 32;
    float* hbuf[2]  = { ws, ws + HB };
    float* skip_acc = ws + 2 * HB;

    static const int dils[12]   = {1, 2, 4, 8, 16, 32, 64, 128, 256, 512, 1024, 2048};
    static const int starts[12] = {6143, 6144, 6146, 6150, 6158, 6174,
                                   6206, 6270, 6398, 6654, 7166, 8190};

    wn_in_conv<<<dim3((NSLOT + 15) / 16, BATCH), dim3(512), 0, stream>>>(
        x, in_w, in_b, hbuf[0], skip_acc);

    for (int l = 0; l < 12; ++l) {
        const int cnt    = TLAST - starts[l] + 1;
        const int nChunk = (cnt + POSC - 1) / POSC;
        wn_layer<<<dim3(nChunk, BATCH), dim3(256), 0, stream>>>(
            hbuf[l & 1], hbuf[(l + 1) & 1],
            dil_w + (size_t)l * 64 * 32 * 2, dil_b + l * 64,
            res_w + (size_t)l * 32 * 32,     res_b + l * 32,
            skip_w + (size_t)l * 32 * 32,    skip_b + l * 32,
            skip_acc, dils[l] / 2, (l == 0) ? 1 : 0, starts[l]);
    }

    wn_head<<<dim3(1), dim3(1024), 0, stream>>>(
        skip_acc, f1_w, f1_b, f2_w, f2_b, (float*)d_out);
}

// Round 3
// 238.468 us; speedup vs baseline: 2.3214x; 1.4874x over previous
//
#include <hip/hip_runtime.h>

// WaveNet single-output inference on MI355X — MFMA bf16-split version.
// Only skip_sum[:, :, 8190] matters => residual stream needed only on
// t in [6143, 8191] (2049 slots), shrinking per layer (starts[] below).
// gate/filt (64x64) and res (32x32) convs as MFMA GEMMs with 2-term bf16
// split (hi+lo, 3 MFMAs) for fp32-grade precision.

typedef __attribute__((ext_vector_type(8))) short short8;
typedef __attribute__((ext_vector_type(4))) short short4v;
typedef __attribute__((ext_vector_type(4))) float f32x4;

#define BASE   6143
#define NSLOT  2049
#define TLAST  8190
#define BATCH  32

__device__ inline ushort bf16hi(float x) {
    union { float f; unsigned u; } v; v.f = x;
    unsigned u = v.u;
    unsigned r = (u + 0x7fffu + ((u >> 16) & 1u)) >> 16;
    return (ushort)r;
}
__device__ inline float bf16f(ushort h) {
    union { unsigned u; float f; } v; v.u = ((unsigned)h) << 16;
    return v.f;
}

// ---------------------------------------------------------------- input conv
__global__ __launch_bounds__(512) void wn_in_conv(
    const float* __restrict__ x, const float* __restrict__ w_,
    const float* __restrict__ b_, float* __restrict__ h0)
{
    __shared__ float xs[16][16];
    const int tid = threadIdx.x;
    const int b   = blockIdx.y;
    const int p   = tid >> 5, c = tid & 31;
    const int t   = BASE + (blockIdx.x * 16 + p);
    const bool valid = (t <= BASE + NSLOT - 1);

    float wreg[16];
    #pragma unroll
    for (int f = 0; f < 16; ++f) wreg[f] = w_[c * 16 + f];

    if (c < 16) xs[p][c] = valid ? x[((size_t)b * 8192 + t) * 16 + c] : 0.f;
    __syncthreads();

    float acc = b_[c];
    #pragma unroll
    for (int f = 0; f < 16; ++f) acc += wreg[f] * xs[p][f];

    if (valid)
        h0[((size_t)b * NSLOT + (t - BASE)) * 32 + c] = acc;
}

// ---------------------------------------------------------------- one layer
// Semantics (validated in rounds 1-2):
//   l==0 (first): tA=t, tB=t+1 (rmax 8191), tR=t+1
//   l>=1:         tA=t-half, tB=t+half (zero beyond 8190), tR=t
// GEMM k-order: k = ic + 32*tap  (A and W staged with the SAME order).
__global__ __launch_bounds__(256) void wn_layer(
    const float* __restrict__ hin, float* __restrict__ hout,
    const float* __restrict__ dw, const float* __restrict__ db,
    const float* __restrict__ rw, const float* __restrict__ rb,
    float* __restrict__ gTL,
    int half, int first, int outStart, int nChunk, int cpb, int layer)
{
    __shared__ __align__(16) ushort Whi[4096], Wlo[4096];   // [n 0..63][k 0..63]
    __shared__ __align__(16) ushort Ahi[4096], Alo[4096];   // [m 0..63][k 0..63]
    __shared__ __align__(16) ushort Ghi[2048], Glo[2048];   // [m 0..63][k 0..31]
    __shared__ __align__(16) ushort Rhi[1024], Rlo[1024];   // [n 0..31][k 0..31]

    const int tid  = threadIdx.x;
    const int b    = blockIdx.y;
    const int lane = tid & 63;
    const int w    = tid >> 6;                 // wave id: mtile
    const float* hb = hin  + (size_t)b * NSLOT * 32;
    float*       ho = hout + (size_t)b * NSLOT * 32;

    // ---- stage gate/filt weights (bf16 hi/lo, XOR-swizzled 16B units)
    {
        const int n = tid >> 2, kb = (tid & 3) * 16;
        const int tap = kb >> 5, ic0 = kb & 31;
        ushort hs[16], ls[16];
        #pragma unroll
        for (int i = 0; i < 16; ++i) {
            float wv = dw[n * 64 + 2 * (ic0 + i) + tap];
            hs[i] = bf16hi(wv);
            ls[i] = bf16hi(wv - bf16f(hs[i]));
        }
        const int u0 = ((kb >> 3)    ) ^ (n & 7);
        const int u1 = ((kb >> 3) + 1) ^ (n & 7);
        short8 h0v, h1v, l0v, l1v;
        #pragma unroll
        for (int i = 0; i < 8; ++i) {
            h0v[i] = (short)hs[i];     h1v[i] = (short)hs[i + 8];
            l0v[i] = (short)ls[i];     l1v[i] = (short)ls[i + 8];
        }
        *(short8*)&Whi[n * 64 + u0 * 8] = h0v;
        *(short8*)&Whi[n * 64 + u1 * 8] = h1v;
        *(short8*)&Wlo[n * 64 + u0 * 8] = l0v;
        *(short8*)&Wlo[n * 64 + u1 * 8] = l1v;
    }
    // ---- stage res weights
    {
        const int n = tid >> 3, k0 = (tid & 7) * 4;
        float4 f = *(const float4*)&rw[n * 32 + k0];
        float vv[4] = { f.x, f.y, f.z, f.w };
        short4v hv, lv;
        #pragma unroll
        for (int i = 0; i < 4; ++i) {
            ushort h = bf16hi(vv[i]);
            hv[i] = (short)h;
            lv[i] = (short)bf16hi(vv[i] - bf16f(h));
        }
        const int u = (k0 >> 3) ^ (n & 3);
        *(short4v*)&Rhi[n * 32 + u * 8 + (k0 & 7)] = hv;
        *(short4v*)&Rlo[n * 32 + u * 8 + (k0 & 7)] = lv;
    }
    __syncthreads();

    // ---- weight fragments, held in VGPRs across chunks
    short8 Bh[4][2], Bl[4][2];                 // [ntile][ktile]
    #pragma unroll
    for (int nt = 0; nt < 4; ++nt)
        #pragma unroll
        for (int kt = 0; kt < 2; ++kt) {
            const int n = (lane & 15) + 16 * nt;
            const int u = (kt * 4 + (lane >> 4)) ^ (n & 7);
            Bh[nt][kt] = *(const short8*)&Whi[n * 64 + u * 8];
            Bl[nt][kt] = *(const short8*)&Wlo[n * 64 + u * 8];
        }
    short8 Rh[2], Rl[2];
    #pragma unroll
    for (int nt = 0; nt < 2; ++nt) {
        const int n = (lane & 15) + 16 * nt;
        const int u = (lane >> 4) ^ (n & 3);
        Rh[nt] = *(const short8*)&Rhi[n * 32 + u * 8];
        Rl[nt] = *(const short8*)&Rlo[n * 32 + u * 8];
    }
    float dbg[2], dbf[2], rbv[2];
    #pragma unroll
    for (int nt = 0; nt < 2; ++nt) {
        dbg[nt] = db[(lane & 15) + 16 * nt];
        dbf[nt] = db[(lane & 15) + 16 * nt + 32];
        rbv[nt] = rb[(lane & 15) + 16 * nt];
    }

    for (int cc = 0; cc < cpb; ++cc) {
        const int chunk = blockIdx.x * cpb + cc;
        if (chunk >= nChunk) break;
        const int t0 = outStart + chunk * 64;

        // ---- stage A (64 pos x 64 k) bf16 hi/lo
        {
            const int m = tid >> 2, kb = (tid & 3) * 16;
            const int tap = kb >> 5, ic0 = kb & 31;
            const int t = t0 + m;
            int slot; bool zero = false;
            if (tap == 0) {
                slot = (first ? t : t - half) - BASE;
            } else {
                const int tB   = first ? (t + 1) : (t + half);
                const int rmax = first ? (BASE + NSLOT - 1) : TLAST;
                zero = (tB > rmax);
                slot = tB - BASE;
            }
            if (slot < 0) slot = 0;
            if (slot > NSLOT - 1) slot = NSLOT - 1;
            float v[16];
            const float* src = hb + (size_t)slot * 32 + ic0;
            #pragma unroll
            for (int i = 0; i < 16; i += 4) {
                float4 f = zero ? make_float4(0.f, 0.f, 0.f, 0.f)
                                : *(const float4*)(src + i);
                v[i] = f.x; v[i + 1] = f.y; v[i + 2] = f.z; v[i + 3] = f.w;
            }
            ushort hs[16], ls[16];
            #pragma unroll
            for (int i = 0; i < 16; ++i) {
                hs[i] = bf16hi(v[i]);
                ls[i] = bf16hi(v[i] - bf16f(hs[i]));
            }
            const int u0 = ((kb >> 3)    ) ^ (m & 7);
            const int u1 = ((kb >> 3) + 1) ^ (m & 7);
            short8 h0v, h1v, l0v, l1v;
            #pragma unroll
            for (int i = 0; i < 8; ++i) {
                h0v[i] = (short)hs[i];     h1v[i] = (short)hs[i + 8];
                l0v[i] = (short)ls[i];     l1v[i] = (short)ls[i + 8];
            }
            *(short8*)&Ahi[m * 64 + u0 * 8] = h0v;
            *(short8*)&Ahi[m * 64 + u1 * 8] = h1v;
            *(short8*)&Alo[m * 64 + u0 * 8] = l0v;
            *(short8*)&Alo[m * 64 + u1 * 8] = l1v;
        }

        // ---- residual taps from global (L2-resident), issued early
        float rv[2][4];
        #pragma unroll
        for (int nt = 0; nt < 2; ++nt)
            #pragma unroll
            for (int r = 0; r < 4; ++r) {
                const int m = 16 * w + 4 * (lane >> 4) + r;
                const int t = t0 + m;
                int slotR = (first ? t + 1 : t) - BASE;
                if (slotR > NSLOT - 1) slotR = NSLOT - 1;
                rv[nt][r] = hb[(size_t)slotR * 32 + (lane & 15) + 16 * nt];
            }

        __syncthreads();

        // ---- A fragments (this wave's 16 rows)
        short8 Ah[2], Al[2];
        #pragma unroll
        for (int kt = 0; kt < 2; ++kt) {
            const int m = 16 * w + (lane & 15);
            const int u = (kt * 4 + (lane >> 4)) ^ (m & 7);
            Ah[kt] = *(const short8*)&Ahi[m * 64 + u * 8];
            Al[kt] = *(const short8*)&Alo[m * 64 + u * 8];
        }

        // ---- gate/filt GEMM: 24 MFMAs (2 kt x 4 nt x 3-split)
        f32x4 acc[4] = { {0,0,0,0}, {0,0,0,0}, {0,0,0,0}, {0,0,0,0} };
        #pragma unroll
        for (int kt = 0; kt < 2; ++kt)
            #pragma unroll
            for (int nt = 0; nt < 4; ++nt) {
                acc[nt] = __builtin_amdgcn_mfma_f32_16x16x32_bf16(Ah[kt], Bh[nt][kt], acc[nt], 0, 0, 0);
                acc[nt] = __builtin_amdgcn_mfma_f32_16x16x32_bf16(Ah[kt], Bl[nt][kt], acc[nt], 0, 0, 0);
                acc[nt] = __builtin_amdgcn_mfma_f32_16x16x32_bf16(Al[kt], Bh[nt][kt], acc[nt], 0, 0, 0);
            }

        // ---- activation + G store (hi/lo) + skip-position capture
        #pragma unroll
        for (int nt = 0; nt < 2; ++nt)
            #pragma unroll
            for (int r = 0; r < 4; ++r) {
                const float gate = acc[nt][r]     + dbg[nt];
                const float filt = acc[nt + 2][r] + dbf[nt];
                const float sg = 1.f / (1.f + __expf(-gate));
                const float th = 2.f / (1.f + __expf(-2.f * filt)) - 1.f;
                const float g  = th * sg;
                const int m = 16 * w + 4 * (lane >> 4) + r;
                const int n = (lane & 15) + 16 * nt;
                ushort gh = bf16hi(g);
                Ghi[m * 32 + ((n >> 3) ^ (m & 3)) * 8 + (n & 7)] = gh;
                Glo[m * 32 + ((n >> 3) ^ (m & 3)) * 8 + (n & 7)] = bf16hi(g - bf16f(gh));
                if (t0 + m == TLAST)
                    gTL[((size_t)layer * BATCH + b) * 32 + n] = g;
            }

        __syncthreads();

        // ---- res GEMM: G (Mx32) x Wr (32x32), 6 MFMAs
        short8 Gh8, Gl8;
        {
            const int m = 16 * w + (lane & 15);
            const int u = (lane >> 4) ^ (m & 3);
            Gh8 = *(const short8*)&Ghi[m * 32 + u * 8];
            Gl8 = *(const short8*)&Glo[m * 32 + u * 8];
        }
        f32x4 accR[2] = { {0,0,0,0}, {0,0,0,0} };
        #pragma unroll
        for (int nt = 0; nt < 2; ++nt) {
            accR[nt] = __builtin_amdgcn_mfma_f32_16x16x32_bf16(Gh8, Rh[nt], accR[nt], 0, 0, 0);
            accR[nt] = __builtin_amdgcn_mfma_f32_16x16x32_bf16(Gh8, Rl[nt], accR[nt], 0, 0, 0);
            accR[nt] = __builtin_amdgcn_mfma_f32_16x16x32_bf16(Gl8, Rh[nt], accR[nt], 0, 0, 0);
        }

        // ---- epilogue: + bias + residual, store fp32
        #pragma unroll
        for (int nt = 0; nt < 2; ++nt)
            #pragma unroll
            for (int r = 0; r < 4; ++r) {
                const int m = 16 * w + 4 * (lane >> 4) + r;
                const int t = t0 + m;
                if (t <= TLAST)
                    ho[(size_t)(t - BASE) * 32 + (lane & 15) + 16 * nt] =
                        accR[nt][r] + rbv[nt] + rv[nt][r];
            }
    }
}

// ---------------------------------------------------------------- head
// skip GEMMs (from captured g at t=8190) + relu/f1/relu/f2
__global__ __launch_bounds__(1024) void wn_head(
    const float* __restrict__ gTL,
    const float* __restrict__ sw, const float* __restrict__ sb,
    const float* __restrict__ f1w, const float* __restrict__ f1b,
    const float* __restrict__ f2w, const float* __restrict__ f2b,
    float* __restrict__ out)
{
    __shared__ float ss[32][33];
    __shared__ float z1[32][33];
    const int tid = threadIdx.x;
    const int b = tid >> 5, s = tid & 31;

    float acc = 0.f;
    for (int l = 0; l < 12; ++l) {
        float a = sb[l * 32 + s];
        #pragma unroll
        for (int ic = 0; ic < 32; ++ic)
            a += sw[l * 1024 + s * 32 + ic] * gTL[((size_t)l * 32 + b) * 32 + ic];
        acc += a;
    }
    ss[b][s] = fmaxf(acc, 0.f);
    __syncthreads();

    float z = f1b[s];
    #pragma unroll
    for (int ic = 0; ic < 32; ++ic) z += f1w[s * 32 + ic] * ss[b][ic];
    z1[b][s] = fmaxf(z, 0.f);
    __syncthreads();

    if (s == 0) {
        float o = f2b[0];
        #pragma unroll
        for (int ic = 0; ic < 32; ++ic) o += f2w[ic] * z1[b][ic];
        out[b] = o;
    }
}

// ---------------------------------------------------------------- launch
extern "C" void kernel_launch(void* const* d_in, const int* in_sizes, int n_in,
                              void* d_out, int out_size, void* d_ws, size_t ws_size,
                              hipStream_t stream)
{
    const float* x      = (const float*)d_in[0];
    const float* in_w   = (const float*)d_in[1];
    const float* in_b   = (const float*)d_in[2];
    const float* dil_w  = (const float*)d_in[3];
    const float* dil_b  = (const float*)d_in[4];
    const float* skip_w = (const float*)d_in[5];
    const float* skip_b = (const float*)d_in[6];
    const float* res_w  = (const float*)d_in[7];
    const float* res_b  = (const float*)d_in[8];
    const float* f1_w   = (const float*)d_in[9];
    const float* f1_b   = (const float*)d_in[10];
    const float* f2_w   = (const float*)d_in[11];
    const float* f2_b   = (const float*)d_in[12];

    float* ws = (float*)d_ws;
    const size_t HB = (size_t)BATCH * NSLOT * 32;
    float* hbuf[2] = { ws, ws + HB };
    float* gTL     = ws + 2 * HB;              // [12][32][32] fp32

    static const int dils[12]   = {1, 2, 4, 8, 16, 32, 64, 128, 256, 512, 1024, 2048};
    static const int starts[12] = {6143, 6144, 6146, 6150, 6158, 6174,
                                   6206, 6270, 6398, 6654, 7166, 8190};

    wn_in_conv<<<dim3((NSLOT + 15) / 16, BATCH), dim3(512), 0, stream>>>(
        x, in_w, in_b, hbuf[0]);

    for (int l = 0; l < 12; ++l) {
        const int cnt    = TLAST - starts[l] + 1;
        const int nChunk = (cnt + 63) / 64;
        const int cpb    = (nChunk * BATCH > 768) ? 2 : 1;
        const int gx     = (nChunk + cpb - 1) / cpb;
        wn_layer<<<dim3(gx, BATCH), dim3(256), 0, stream>>>(
            hbuf[l & 1], hbuf[(l + 1) & 1],
            dil_w + (size_t)l * 64 * 32 * 2, dil_b + l * 64,
            res_w + (size_t)l * 32 * 32,     res_b + l * 32,
            gTL, dils[l] / 2, (l == 0) ? 1 : 0, starts[l], nChunk, cpb, l);
    }

    wn_head<<<dim3(1), dim3(1024), 0, stream>>>(
        gTL, skip_w, skip_b, f1_w, f1_b, f2_w, f2_b, (float*)d_out);
}

// Round 4
// 204.776 us; speedup vs baseline: 2.7034x; 1.1645x over previous
//
#include <hip/hip_runtime.h>

// WaveNet single-output inference on MI355X — barrier-free MFMA version.
// Only skip_sum[:, :, 8190] matters => residual stream needed only on
// t in [6143, 8191] (2049 slots), shrinking per layer (starts[] below).
// h stored as bf16 hi/lo split pairs (recon err ~2^-18); gate/filt (64x64)
// and res (32x32) convs as MFMA GEMMs with 2-term bf16 split (3 MFMAs).
// A/B fragments loaded directly from global with the SAME assumed lane->k
// mapping on both operands (k-permutation cancels; validated round 3).

typedef __attribute__((ext_vector_type(8))) short short8;
typedef __attribute__((ext_vector_type(4))) float f32x4;

#define BASE   6143
#define NSLOT  2049
#define TLAST  8190
#define BATCH  32

__device__ inline ushort bf16hi(float x) {
    union { float f; unsigned u; } v; v.f = x;
    const unsigned u = v.u;
    return (ushort)((u + 0x7fffu + ((u >> 16) & 1u)) >> 16);
}
__device__ inline float bf16f(ushort h) {
    union { unsigned u; float f; } v; v.u = ((unsigned)h) << 16;
    return v.f;
}

// ---------------------------------------------------------------- weight prep
__global__ __launch_bounds__(256) void wn_prep(
    const float* __restrict__ dil_w, const float* __restrict__ res_w,
    ushort* __restrict__ wdh, ushort* __restrict__ wdl,
    ushort* __restrict__ wrh, ushort* __restrict__ wrl)
{
    const int idx = blockIdx.x * 256 + threadIdx.x;
    if (idx < 12 * 4096) {
        const int l = idx >> 12, rem = idx & 4095, n = rem >> 6, k = rem & 63;
        const int tap = k >> 5, ic = k & 31;
        const float v = dil_w[((size_t)l * 64 + n) * 64 + 2 * ic + tap];
        const ushort h = bf16hi(v);
        wdh[idx] = h;
        wdl[idx] = bf16hi(v - bf16f(h));
    } else if (idx < 12 * 4096 + 12 * 1024) {
        const int j = idx - 12 * 4096;
        const float v = res_w[j];
        const ushort h = bf16hi(v);
        wrh[j] = h;
        wrl[j] = bf16hi(v - bf16f(h));
    }
}

// ---------------------------------------------------------------- input conv
__global__ __launch_bounds__(512) void wn_in_conv(
    const float* __restrict__ x, const float* __restrict__ w_,
    const float* __restrict__ b_, ushort* __restrict__ hh,
    ushort* __restrict__ hl)
{
    __shared__ float xs[16][16];
    const int tid = threadIdx.x;
    const int b   = blockIdx.y;
    const int p   = tid >> 5, c = tid & 31;
    const int t   = BASE + (blockIdx.x * 16 + p);
    const bool valid = (t <= BASE + NSLOT - 1);

    float wreg[16];
    #pragma unroll
    for (int f = 0; f < 16; ++f) wreg[f] = w_[c * 16 + f];

    if (c < 16) xs[p][c] = valid ? x[((size_t)b * 8192 + t) * 16 + c] : 0.f;
    __syncthreads();

    float acc = b_[c];
    #pragma unroll
    for (int f = 0; f < 16; ++f) acc += wreg[f] * xs[p][f];

    if (valid) {
        const size_t off = (size_t)b * NSLOT * 32 + (size_t)(t - BASE) * 32 + c;
        const ushort h = bf16hi(acc);
        hh[off] = h;
        hl[off] = bf16hi(acc - bf16f(h));
    }
}

// ---------------------------------------------------------------- one layer
// Semantics (validated rounds 1-3):
//   l==0 (first): tA=t, tB=t+1 (rmax 8191), tR=t+1
//   l>=1:         tA=t-half, tB=t+half (zero beyond 8190), tR=t
// GEMM k-order: k = ic + 32*tap; fragments: row = lane&15, k-octet = lane>>4.
// No __syncthreads anywhere: LDS only for per-wave G transpose.
__global__ __launch_bounds__(256) void wn_layer(
    const ushort* __restrict__ hih, const ushort* __restrict__ hil,
    ushort* __restrict__ hoh, ushort* __restrict__ hol,
    const ushort* __restrict__ wdh, const ushort* __restrict__ wdl,
    const ushort* __restrict__ wrh, const ushort* __restrict__ wrl,
    const float* __restrict__ db, const float* __restrict__ rb,
    float* __restrict__ gTL,
    int half, int first, int outStart, int layer)
{
    __shared__ __align__(16) ushort Gh[4][16 * 40];   // per-wave, stride 40
    __shared__ __align__(16) ushort Gl[4][16 * 40];

    const int tid  = threadIdx.x;
    const int lane = tid & 63;
    const int w    = tid >> 6;
    const int b    = blockIdx.y;
    const int nl   = lane & 15, o = lane >> 4;
    const int t0   = outStart + blockIdx.x * 64;
    const size_t hbase = (size_t)b * NSLOT * 32;

    // ---- weight fragments straight from pre-split global
    short8 Bh[4][2], Bl[4][2], Rh[2], Rl[2];
    #pragma unroll
    for (int nt = 0; nt < 4; ++nt)
        #pragma unroll
        for (int kt = 0; kt < 2; ++kt) {
            const int n = nl + 16 * nt;
            Bh[nt][kt] = *(const short8*)&wdh[n * 64 + kt * 32 + o * 8];
            Bl[nt][kt] = *(const short8*)&wdl[n * 64 + kt * 32 + o * 8];
        }
    #pragma unroll
    for (int nt = 0; nt < 2; ++nt) {
        const int n = nl + 16 * nt;
        Rh[nt] = *(const short8*)&wrh[n * 32 + o * 8];
        Rl[nt] = *(const short8*)&wrl[n * 32 + o * 8];
    }
    float dbg[2], dbf[2], rbv[2];
    #pragma unroll
    for (int nt = 0; nt < 2; ++nt) {
        dbg[nt] = db[nl + 16 * nt];
        dbf[nt] = db[nl + 16 * nt + 32];
        rbv[nt] = rb[nl + 16 * nt];
    }

    const int aOff = first ? 0 : half;
    const int bOff = first ? 1 : half;
    const int rmax = first ? (BASE + NSLOT - 1) : TLAST;

    // ---- A fragments direct from global (this lane's m-row = nl)
    const int tA = t0 + 16 * w + nl;
    int sA = tA - aOff - BASE;
    if (sA > NSLOT - 1) sA = NSLOT - 1;
    const int  tB = tA + bOff;
    const bool zB = (tB > rmax);
    int sB = tB - BASE;
    if (sB > NSLOT - 1) sB = NSLOT - 1;

    short8 Ah[2], Al[2];
    Ah[0] = *(const short8*)&hih[hbase + (size_t)sA * 32 + o * 8];
    Al[0] = *(const short8*)&hil[hbase + (size_t)sA * 32 + o * 8];
    const short8 z8 = {0, 0, 0, 0, 0, 0, 0, 0};
    Ah[1] = zB ? z8 : *(const short8*)&hih[hbase + (size_t)sB * 32 + o * 8];
    Al[1] = zB ? z8 : *(const short8*)&hil[hbase + (size_t)sB * 32 + o * 8];

    // ---- residual taps (bf16-split recon), row m = 4*o + r within wave tile
    float rv[2][4];
    #pragma unroll
    for (int nt = 0; nt < 2; ++nt)
        #pragma unroll
        for (int r = 0; r < 4; ++r) {
            const int t = t0 + 16 * w + 4 * o + r;
            int slotR = (first ? t + 1 : t) - BASE;
            if (slotR > NSLOT - 1) slotR = NSLOT - 1;
            const size_t off = hbase + (size_t)slotR * 32 + nl + 16 * nt;
            rv[nt][r] = bf16f(hih[off]) + bf16f(hil[off]);
        }

    // ---- gate/filt GEMM: 24 MFMAs (2 kt x 4 nt x 3-split)
    f32x4 acc[4] = { {0,0,0,0}, {0,0,0,0}, {0,0,0,0}, {0,0,0,0} };
    #pragma unroll
    for (int kt = 0; kt < 2; ++kt)
        #pragma unroll
        for (int nt = 0; nt < 4; ++nt) {
            acc[nt] = __builtin_amdgcn_mfma_f32_16x16x32_bf16(Ah[kt], Bh[nt][kt], acc[nt], 0, 0, 0);
            acc[nt] = __builtin_amdgcn_mfma_f32_16x16x32_bf16(Ah[kt], Bl[nt][kt], acc[nt], 0, 0, 0);
            acc[nt] = __builtin_amdgcn_mfma_f32_16x16x32_bf16(Al[kt], Bh[nt][kt], acc[nt], 0, 0, 0);
        }

    // ---- activation + per-wave G transpose (LDS, own wave only) + skip tap
    #pragma unroll
    for (int nt = 0; nt < 2; ++nt)
        #pragma unroll
        for (int r = 0; r < 4; ++r) {
            const float gate = acc[nt][r]     + dbg[nt];
            const float filt = acc[nt + 2][r] + dbf[nt];
            const float sg = 1.f / (1.f + __expf(-gate));
            const float th = 2.f / (1.f + __expf(-2.f * filt)) - 1.f;
            const float g  = th * sg;
            const int ml = 4 * o + r;
            const int n  = nl + 16 * nt;
            const ushort gh = bf16hi(g);
            Gh[w][ml * 40 + n] = gh;
            Gl[w][ml * 40 + n] = bf16hi(g - bf16f(gh));
            if (t0 + 16 * w + ml == TLAST)
                gTL[((size_t)layer * BATCH + b) * 32 + n] = g;
        }

    // ---- res GEMM: G (16x32) x Wr (32x32), 6 MFMAs (no barrier: same wave)
    const short8 Gh8 = *(const short8*)&Gh[w][nl * 40 + o * 8];
    const short8 Gl8 = *(const short8*)&Gl[w][nl * 40 + o * 8];
    f32x4 accR[2] = { {0,0,0,0}, {0,0,0,0} };
    #pragma unroll
    for (int nt = 0; nt < 2; ++nt) {
        accR[nt] = __builtin_amdgcn_mfma_f32_16x16x32_bf16(Gh8, Rh[nt], accR[nt], 0, 0, 0);
        accR[nt] = __builtin_amdgcn_mfma_f32_16x16x32_bf16(Gh8, Rl[nt], accR[nt], 0, 0, 0);
        accR[nt] = __builtin_amdgcn_mfma_f32_16x16x32_bf16(Gl8, Rh[nt], accR[nt], 0, 0, 0);
    }

    // ---- epilogue: + bias + residual, store bf16 hi/lo split
    #pragma unroll
    for (int nt = 0; nt < 2; ++nt)
        #pragma unroll
        for (int r = 0; r < 4; ++r) {
            const int t = t0 + 16 * w + 4 * o + r;
            if (t <= TLAST) {
                const float hv = accR[nt][r] + rbv[nt] + rv[nt][r];
                const size_t off = hbase + (size_t)(t - BASE) * 32 + nl + 16 * nt;
                const ushort hh = bf16hi(hv);
                hoh[off] = hh;
                hol[off] = bf16hi(hv - bf16f(hh));
            }
        }
}

// ---------------------------------------------------------------- head
// one block per batch: skip GEMMs from captured g + relu/f1/relu/f2
__global__ __launch_bounds__(64) void wn_head(
    const float* __restrict__ gTL,
    const float* __restrict__ sw, const float* __restrict__ sb,
    const float* __restrict__ f1w, const float* __restrict__ f1b,
    const float* __restrict__ f2w, const float* __restrict__ f2b,
    float* __restrict__ out)
{
    __shared__ float ss[32], z1[32];
    const int tid = threadIdx.x;
    const int b = blockIdx.x;

    if (tid < 32) {
        float acc = 0.f;
        for (int l = 0; l < 12; ++l) {
            float a = sb[l * 32 + tid];
            #pragma unroll
            for (int ic = 0; ic < 32; ++ic)
                a += sw[l * 1024 + tid * 32 + ic] * gTL[((size_t)l * 32 + b) * 32 + ic];
            acc += a;
        }
        ss[tid] = fmaxf(acc, 0.f);
    }
    __syncthreads();

    if (tid < 32) {
        float z = f1b[tid];
        #pragma unroll
        for (int ic = 0; ic < 32; ++ic) z += f1w[tid * 32 + ic] * ss[ic];
        z1[tid] = fmaxf(z, 0.f);
    }
    __syncthreads();

    if (tid == 0) {
        float o = f2b[0];
        #pragma unroll
        for (int ic = 0; ic < 32; ++ic) o += f2w[ic] * z1[ic];
        out[b] = o;
    }
}

// ---------------------------------------------------------------- launch
extern "C" void kernel_launch(void* const* d_in, const int* in_sizes, int n_in,
                              void* d_out, int out_size, void* d_ws, size_t ws_size,
                              hipStream_t stream)
{
    const float* x      = (const float*)d_in[0];
    const float* in_w   = (const float*)d_in[1];
    const float* in_b   = (const float*)d_in[2];
    const float* dil_w  = (const float*)d_in[3];
    const float* dil_b  = (const float*)d_in[4];
    const float* skip_w = (const float*)d_in[5];
    const float* skip_b = (const float*)d_in[6];
    const float* res_w  = (const float*)d_in[7];
    const float* res_b  = (const float*)d_in[8];
    const float* f1_w   = (const float*)d_in[9];
    const float* f1_b   = (const float*)d_in[10];
    const float* f2_w   = (const float*)d_in[11];
    const float* f2_b   = (const float*)d_in[12];

    const size_t HB = (size_t)BATCH * NSLOT * 32;   // elements per h buffer
    char* p = (char*)d_ws;
    ushort* hh0 = (ushort*)p;  p += HB * 2;
    ushort* hl0 = (ushort*)p;  p += HB * 2;
    ushort* hh1 = (ushort*)p;  p += HB * 2;
    ushort* hl1 = (ushort*)p;  p += HB * 2;
    ushort* wdh = (ushort*)p;  p += 12 * 4096 * 2;
    ushort* wdl = (ushort*)p;  p += 12 * 4096 * 2;
    ushort* wrh = (ushort*)p;  p += 12 * 1024 * 2;
    ushort* wrl = (ushort*)p;  p += 12 * 1024 * 2;
    float*  gTL = (float*)p;                        // [12][32][32]

    ushort* HH[2] = { hh0, hh1 };
    ushort* HL[2] = { hl0, hl1 };

    static const int dils[12]   = {1, 2, 4, 8, 16, 32, 64, 128, 256, 512, 1024, 2048};
    static const int starts[12] = {6143, 6144, 6146, 6150, 6158, 6174,
                                   6206, 6270, 6398, 6654, 7166, 8190};

    wn_prep<<<dim3((12 * 4096 + 12 * 1024 + 255) / 256), dim3(256), 0, stream>>>(
        dil_w, res_w, wdh, wdl, wrh, wrl);

    wn_in_conv<<<dim3((NSLOT + 15) / 16, BATCH), dim3(512), 0, stream>>>(
        x, in_w, in_b, hh0, hl0);

    for (int l = 0; l < 12; ++l) {
        const int cnt    = TLAST - starts[l] + 1;
        const int nChunk = (cnt + 63) / 64;
        wn_layer<<<dim3(nChunk, BATCH), dim3(256), 0, stream>>>(
            HH[l & 1], HL[l & 1], HH[(l + 1) & 1], HL[(l + 1) & 1],
            wdh + (size_t)l * 4096, wdl + (size_t)l * 4096,
            wrh + (size_t)l * 1024, wrl + (size_t)l * 1024,
            dil_b + l * 64, res_b + l * 32,
            gTL, dils[l] / 2, (l == 0) ? 1 : 0, starts[l], l);
    }

    wn_head<<<dim3(BATCH), dim3(64), 0, stream>>>(
        gTL, skip_w, skip_b, f1_w, f1_b, f2_w, f2_b, (float*)d_out);
}

// Round 6
// 74.427 us; speedup vs baseline: 7.4380x; 2.7514x over previous
//
#include <hip/hip_runtime.h>

// WaveNet single-output inference on MI355X — sparse-tree fused version.
// Only skip_sum[:, :, 8190] matters. The exact dependency set of that value
// per layer is an arithmetic progression with stride = dilation/2:
//   need_l (input positions of layer l):
//     l=0: [6143,8191] dense; l=1: AP(6143,1); l=2: AP(6144,2); l=3: AP(6146,4)
//     l=4: AP(6150,8); l=5: AP(6158,16); l=6: AP(6174,32) (64 pts);
//     l=7: AP(6206,64) (32); ... l=11: {7166, 8190} (2); h_12 never needed.
// In compacted coordinates every layer is: out[j] <- W0*in[2j] + W1*in[2j+2],
// residual in[2j+1]  (layer 0: in[j], in[j+1], residual in[j+1]).
// Kernel A: in_conv + layers 0-5 per block via exact-fit halo pyramid
//           (96->95->47->23->11->5->2) producing 2 compact h6 outputs.
// Kernel B: layers 6-11 + skip + f1/f2 head, one block per batch, all in LDS.
// Round-5 bug fixed here: fuseB's c6->LDS staging only copied 2 of 4 short8
// chunks per 32-channel row (channels 8-15/24-31 were garbage). Now 4 chunks.

typedef __attribute__((ext_vector_type(8))) short short8;
typedef __attribute__((ext_vector_type(4))) float f32x4;

#define TLAST  8190
#define BATCH  32

__device__ inline ushort bf16hi(float x) {
    union { float f; unsigned u; } v; v.f = x;
    const unsigned u = v.u;
    return (ushort)((u + 0x7fffu + ((u >> 16) & 1u)) >> 16);
}
__device__ inline float bf16f(ushort h) {
    union { unsigned u; float f; } v; v.u = ((unsigned)h) << 16;
    return v.f;
}
__device__ inline int imin(int a, int b) { return a < b ? a : b; }

// ---------------------------------------------------------------- weight prep
// k-order for gate/filt GEMM: k = ic + 32*tap (tap 0 = left tap t-d/2).
__global__ __launch_bounds__(256) void wn_prep(
    const float* __restrict__ dil_w, const float* __restrict__ res_w,
    ushort* __restrict__ wdh, ushort* __restrict__ wdl,
    ushort* __restrict__ wrh, ushort* __restrict__ wrl)
{
    const int idx = blockIdx.x * 256 + threadIdx.x;
    if (idx < 12 * 4096) {
        const int l = idx >> 12, rem = idx & 4095, n = rem >> 6, k = rem & 63;
        const int tap = k >> 5, ic = k & 31;
        const float v = dil_w[((size_t)l * 64 + n) * 64 + 2 * ic + tap];
        const ushort h = bf16hi(v);
        wdh[idx] = h;
        wdl[idx] = bf16hi(v - bf16f(h));
    } else if (idx < 12 * 4096 + 12 * 1024) {
        const int j = idx - 12 * 4096;
        const float v = res_w[j];
        const ushort h = bf16hi(v);
        wrh[j] = h;
        wrl[j] = bf16hi(v - bf16f(h));
    }
}

// ---------------------------------------------------------------- phase A
// One block = one (chunk, batch): produces h6 at t = t6a, t6a+32.
// Dense window H0: t in [t6a-31, t6a+64] (96 rows). Exact-fit pyramid.
__global__ __launch_bounds__(256) void wn_fuseA(
    const float* __restrict__ x, const float* __restrict__ in_w,
    const float* __restrict__ in_b,
    const ushort* __restrict__ wdh, const ushort* __restrict__ wdl,
    const ushort* __restrict__ wrh, const ushort* __restrict__ wrl,
    const float* __restrict__ dil_b, const float* __restrict__ res_b,
    ushort* __restrict__ c6h, ushort* __restrict__ c6l,
    float* __restrict__ gTL)
{
    __shared__ __align__(16) ushort HAh[96 * 40], HAl[96 * 40];
    __shared__ __align__(16) ushort HBh[96 * 40], HBl[96 * 40];
    __shared__ __align__(16) ushort sGh[4][16 * 40], sGl[4][16 * 40];
    __shared__ __align__(16) float  xs[96 * 20];

    const int tid  = threadIdx.x;
    const int cc   = blockIdx.x, b = blockIdx.y;
    const int lane = tid & 63, w = tid >> 6;
    const int nl   = lane & 15, o = lane >> 4;
    const int t6a  = 6174 + cc * 64;
    const int a0   = t6a - 31;            // global t of H0 row 0

    // ---- stage x (96 pos x 16 ch, fp32)
    for (int i = tid; i < 384; i += 256) {
        const int p = i >> 2, c4 = (i & 3) * 4;
        const int t = a0 + p;
        float4 v = make_float4(0.f, 0.f, 0.f, 0.f);
        if (t <= 8191) v = *(const float4*)&x[((size_t)b * 8192 + t) * 16 + c4];
        *(float4*)&xs[p * 20 + c4] = v;
    }
    __syncthreads();

    // ---- in_conv -> HA (bf16 hi/lo)
    {
        const int c = tid & 31, pg = tid >> 5;
        float wr[16];
        #pragma unroll
        for (int f = 0; f < 16; ++f) wr[f] = in_w[c * 16 + f];
        const float bias = in_b[c];
        #pragma unroll
        for (int q = 0; q < 12; ++q) {
            const int p = pg + 8 * q;     // 0..95
            float acc = bias;
            #pragma unroll
            for (int f4 = 0; f4 < 4; ++f4) {
                const float4 xv = *(const float4*)&xs[p * 20 + f4 * 4];
                acc += wr[f4*4+0]*xv.x + wr[f4*4+1]*xv.y
                     + wr[f4*4+2]*xv.z + wr[f4*4+3]*xv.w;
            }
            const ushort hh = bf16hi(acc);
            HAh[p * 40 + c] = hh;
            HAl[p * 40 + c] = bf16hi(acc - bf16f(hh));
        }
    }
    __syncthreads();

    const int nInA[6]  = {96, 95, 47, 23, 11, 5};
    const int nOutA[6] = {95, 47, 23, 11, 5, 2};
    const int nTA[6]   = {6, 3, 2, 1, 1, 1};
    const int offA[6]  = {0, 1, 3, 7, 15, 31};   // out-start offset from a0
    const int sA_[6]   = {1, 2, 4, 8, 16, 32};   // out stride

    #pragma unroll
    for (int l = 0; l < 6; ++l) {
        const ushort* Hih = (l & 1) ? HBh : HAh;
        const ushort* Hil = (l & 1) ? HBl : HAl;
        ushort* Hoh = (l & 1) ? HAh : HBh;
        ushort* Hol = (l & 1) ? HAl : HBl;
        const int nIn = nInA[l], nOut = nOutA[l];
        const int aO  = a0 + offA[l], sO = sA_[l];
        const int bOff = (l == 0) ? 1 : (sO >> 1);
        const int rmx  = (l == 0) ? 8191 : TLAST;

        // weight fragments from pre-split global
        const ushort* pdh = wdh + l * 4096;
        const ushort* pdl = wdl + l * 4096;
        const ushort* prh = wrh + l * 1024;
        const ushort* prl = wrl + l * 1024;
        short8 Bh[4][2], Bl[4][2], Rh[2], Rl[2];
        #pragma unroll
        for (int nt = 0; nt < 4; ++nt)
            #pragma unroll
            for (int kt = 0; kt < 2; ++kt) {
                const int n = nl + 16 * nt;
                Bh[nt][kt] = *(const short8*)&pdh[n * 64 + kt * 32 + o * 8];
                Bl[nt][kt] = *(const short8*)&pdl[n * 64 + kt * 32 + o * 8];
            }
        #pragma unroll
        for (int nt = 0; nt < 2; ++nt) {
            const int n = nl + 16 * nt;
            Rh[nt] = *(const short8*)&prh[n * 32 + o * 8];
            Rl[nt] = *(const short8*)&prl[n * 32 + o * 8];
        }
        float dbg[2], dbf[2], rbv[2];
        #pragma unroll
        for (int nt = 0; nt < 2; ++nt) {
            dbg[nt] = dil_b[l * 64 + nl + 16 * nt];
            dbf[nt] = dil_b[l * 64 + nl + 16 * nt + 32];
            rbv[nt] = res_b[l * 32 + nl + 16 * nt];
        }

        for (int tt = w; tt < nTA[l]; tt += 4) {
            // ---- A fragments from LDS (compact taps)
            const int joF = tt * 16 + nl;
            const int j0 = imin((l == 0) ? joF : 2 * joF, nIn - 1);
            const int j1 = imin((l == 0) ? joF + 1 : 2 * joF + 2, nIn - 1);
            const bool zB = (aO + joF * sO + bOff) > rmx;
            const short8 z8 = {0,0,0,0,0,0,0,0};
            short8 Ah[2], Al[2];
            Ah[0] = *(const short8*)&Hih[j0 * 40 + o * 8];
            Al[0] = *(const short8*)&Hil[j0 * 40 + o * 8];
            Ah[1] = zB ? z8 : *(const short8*)&Hih[j1 * 40 + o * 8];
            Al[1] = zB ? z8 : *(const short8*)&Hil[j1 * 40 + o * 8];

            // ---- gate/filt GEMM (bf16-split, 24 MFMAs)
            f32x4 acc[4] = {{0,0,0,0},{0,0,0,0},{0,0,0,0},{0,0,0,0}};
            #pragma unroll
            for (int kt = 0; kt < 2; ++kt)
                #pragma unroll
                for (int nt = 0; nt < 4; ++nt) {
                    acc[nt] = __builtin_amdgcn_mfma_f32_16x16x32_bf16(Ah[kt], Bh[nt][kt], acc[nt], 0, 0, 0);
                    acc[nt] = __builtin_amdgcn_mfma_f32_16x16x32_bf16(Ah[kt], Bl[nt][kt], acc[nt], 0, 0, 0);
                    acc[nt] = __builtin_amdgcn_mfma_f32_16x16x32_bf16(Al[kt], Bh[nt][kt], acc[nt], 0, 0, 0);
                }

            // ---- activation + per-wave G transpose + gTL capture
            #pragma unroll
            for (int nt = 0; nt < 2; ++nt)
                #pragma unroll
                for (int r = 0; r < 4; ++r) {
                    const float gate = acc[nt][r]     + dbg[nt];
                    const float filt = acc[nt + 2][r] + dbf[nt];
                    const float sg = 1.f / (1.f + __expf(-gate));
                    const float th = 2.f / (1.f + __expf(-2.f * filt)) - 1.f;
                    const float g  = th * sg;
                    const int ml = 4 * o + r;
                    const int n  = nl + 16 * nt;
                    const ushort gh = bf16hi(g);
                    sGh[w][ml * 40 + n] = gh;
                    sGl[w][ml * 40 + n] = bf16hi(g - bf16f(gh));
                    const int joG = tt * 16 + ml;
                    if (joG < nOut && (aO + joG * sO) == TLAST)
                        gTL[((size_t)l * BATCH + b) * 32 + n] = g;
                }

            // ---- res GEMM (6 MFMAs, same-wave LDS, no barrier)
            const short8 Gh8 = *(const short8*)&sGh[w][nl * 40 + o * 8];
            const short8 Gl8 = *(const short8*)&sGl[w][nl * 40 + o * 8];
            f32x4 accR[2] = {{0,0,0,0},{0,0,0,0}};
            #pragma unroll
            for (int nt = 0; nt < 2; ++nt) {
                accR[nt] = __builtin_amdgcn_mfma_f32_16x16x32_bf16(Gh8, Rh[nt], accR[nt], 0, 0, 0);
                accR[nt] = __builtin_amdgcn_mfma_f32_16x16x32_bf16(Gh8, Rl[nt], accR[nt], 0, 0, 0);
                accR[nt] = __builtin_amdgcn_mfma_f32_16x16x32_bf16(Gl8, Rh[nt], accR[nt], 0, 0, 0);
            }

            // ---- epilogue: + bias + residual (compact idx 2j+1), store
            #pragma unroll
            for (int nt = 0; nt < 2; ++nt)
                #pragma unroll
                for (int r = 0; r < 4; ++r) {
                    const int ml  = 4 * o + r;
                    const int joE = tt * 16 + ml;
                    const int jres = imin((l == 0) ? joE + 1 : 2 * joE + 1, nIn - 1);
                    const int n = nl + 16 * nt;
                    const float resv = bf16f(Hih[jres * 40 + n]) + bf16f(Hil[jres * 40 + n]);
                    const float hv = accR[nt][r] + rbv[nt] + resv;
                    const ushort hh = bf16hi(hv);
                    const ushort hl = bf16hi(hv - bf16f(hh));
                    Hoh[joE * 40 + n] = hh;
                    Hol[joE * 40 + n] = hl;
                    if (l == 5 && joE < 2) {
                        const size_t go = ((size_t)b * 64 + cc * 2 + joE) * 32 + n;
                        c6h[go] = hh;
                        c6l[go] = hl;
                    }
                }
        }
        __syncthreads();
    }
}

// ---------------------------------------------------------------- phase B
// One block per batch: layers 6-11 (compact, in LDS) + skip sum + f1/f2 head.
__global__ __launch_bounds__(256) void wn_fuseB(
    const ushort* __restrict__ c6h, const ushort* __restrict__ c6l,
    const ushort* __restrict__ wdh, const ushort* __restrict__ wdl,
    const ushort* __restrict__ wrh, const ushort* __restrict__ wrl,
    const float* __restrict__ dil_b, const float* __restrict__ res_b,
    const float* __restrict__ gTL,
    const float* __restrict__ sw, const float* __restrict__ sb,
    const float* __restrict__ f1w, const float* __restrict__ f1b,
    const float* __restrict__ f2w, const float* __restrict__ f2b,
    float* __restrict__ out)
{
    __shared__ __align__(16) ushort HAh[64 * 40], HAl[64 * 40];
    __shared__ __align__(16) ushort HBh[64 * 40], HBl[64 * 40];
    __shared__ __align__(16) ushort sGh[4][16 * 40], sGl[4][16 * 40];
    __shared__ float gcap[6][33];
    __shared__ float ss[32], z1[32];

    const int tid  = threadIdx.x, b = blockIdx.x;
    const int lane = tid & 63, w = tid >> 6;
    const int nl   = lane & 15, o = lane >> 4;

    // FIXED (round-5 bug): 4 short8 chunks per 32-channel row, not 2.
    for (int i = tid; i < 256; i += 256) {
        const int row = i >> 2, c8 = (i & 3) * 8;
        *(short8*)&HAh[row * 40 + c8] = *(const short8*)&c6h[((size_t)b * 64 + row) * 32 + c8];
        *(short8*)&HAl[row * 40 + c8] = *(const short8*)&c6l[((size_t)b * 64 + row) * 32 + c8];
    }
    __syncthreads();

    const int nInB[6]  = {64, 32, 16, 8, 4, 2};
    const int nOutB[6] = {32, 16, 8, 4, 2, 1};
    const int nTB[6]   = {2, 1, 1, 1, 1, 1};
    const int aOB[6]   = {6206, 6270, 6398, 6654, 7166, 8190};
    const int sOB[6]   = {64, 128, 256, 512, 1024, 2048};

    #pragma unroll
    for (int ll = 0; ll < 6; ++ll) {
        const int l = ll + 6;
        const ushort* Hih = (ll & 1) ? HBh : HAh;
        const ushort* Hil = (ll & 1) ? HBl : HAl;
        ushort* Hoh = (ll & 1) ? HAh : HBh;
        ushort* Hol = (ll & 1) ? HAl : HBl;
        const int nIn = nInB[ll], nOut = nOutB[ll];
        const int aO = aOB[ll], sO = sOB[ll];
        const int bOff = sO >> 1;

        const ushort* pdh = wdh + l * 4096;
        const ushort* pdl = wdl + l * 4096;
        const ushort* prh = wrh + l * 1024;
        const ushort* prl = wrl + l * 1024;
        short8 Bh[4][2], Bl[4][2], Rh[2], Rl[2];
        #pragma unroll
        for (int nt = 0; nt < 4; ++nt)
            #pragma unroll
            for (int kt = 0; kt < 2; ++kt) {
                const int n = nl + 16 * nt;
                Bh[nt][kt] = *(const short8*)&pdh[n * 64 + kt * 32 + o * 8];
                Bl[nt][kt] = *(const short8*)&pdl[n * 64 + kt * 32 + o * 8];
            }
        #pragma unroll
        for (int nt = 0; nt < 2; ++nt) {
            const int n = nl + 16 * nt;
            Rh[nt] = *(const short8*)&prh[n * 32 + o * 8];
            Rl[nt] = *(const short8*)&prl[n * 32 + o * 8];
        }
        float dbg[2], dbf[2], rbv[2];
        #pragma unroll
        for (int nt = 0; nt < 2; ++nt) {
            dbg[nt] = dil_b[l * 64 + nl + 16 * nt];
            dbf[nt] = dil_b[l * 64 + nl + 16 * nt + 32];
            rbv[nt] = res_b[l * 32 + nl + 16 * nt];
        }

        for (int tt = w; tt < nTB[ll]; tt += 4) {
            const int joF = tt * 16 + nl;
            const int j0 = imin(2 * joF, nIn - 1);
            const int j1 = imin(2 * joF + 2, nIn - 1);
            const bool zB = (aO + joF * sO + bOff) > TLAST;
            const short8 z8 = {0,0,0,0,0,0,0,0};
            short8 Ah[2], Al[2];
            Ah[0] = *(const short8*)&Hih[j0 * 40 + o * 8];
            Al[0] = *(const short8*)&Hil[j0 * 40 + o * 8];
            Ah[1] = zB ? z8 : *(const short8*)&Hih[j1 * 40 + o * 8];
            Al[1] = zB ? z8 : *(const short8*)&Hil[j1 * 40 + o * 8];

            f32x4 acc[4] = {{0,0,0,0},{0,0,0,0},{0,0,0,0},{0,0,0,0}};
            #pragma unroll
            for (int kt = 0; kt < 2; ++kt)
                #pragma unroll
                for (int nt = 0; nt < 4; ++nt) {
                    acc[nt] = __builtin_amdgcn_mfma_f32_16x16x32_bf16(Ah[kt], Bh[nt][kt], acc[nt], 0, 0, 0);
                    acc[nt] = __builtin_amdgcn_mfma_f32_16x16x32_bf16(Ah[kt], Bl[nt][kt], acc[nt], 0, 0, 0);
                    acc[nt] = __builtin_amdgcn_mfma_f32_16x16x32_bf16(Al[kt], Bh[nt][kt], acc[nt], 0, 0, 0);
                }

            #pragma unroll
            for (int nt = 0; nt < 2; ++nt)
                #pragma unroll
                for (int r = 0; r < 4; ++r) {
                    const float gate = acc[nt][r]     + dbg[nt];
                    const float filt = acc[nt + 2][r] + dbf[nt];
                    const float sg = 1.f / (1.f + __expf(-gate));
                    const float th = 2.f / (1.f + __expf(-2.f * filt)) - 1.f;
                    const float g  = th * sg;
                    const int ml = 4 * o + r;
                    const int n  = nl + 16 * nt;
                    const ushort gh = bf16hi(g);
                    sGh[w][ml * 40 + n] = gh;
                    sGl[w][ml * 40 + n] = bf16hi(g - bf16f(gh));
                    const int joG = tt * 16 + ml;
                    if (joG < nOut && (aO + joG * sO) == TLAST)
                        gcap[ll][n] = g;
                }

            if (ll < 5) {
                const short8 Gh8 = *(const short8*)&sGh[w][nl * 40 + o * 8];
                const short8 Gl8 = *(const short8*)&sGl[w][nl * 40 + o * 8];
                f32x4 accR[2] = {{0,0,0,0},{0,0,0,0}};
                #pragma unroll
                for (int nt = 0; nt < 2; ++nt) {
                    accR[nt] = __builtin_amdgcn_mfma_f32_16x16x32_bf16(Gh8, Rh[nt], accR[nt], 0, 0, 0);
                    accR[nt] = __builtin_amdgcn_mfma_f32_16x16x32_bf16(Gh8, Rl[nt], accR[nt], 0, 0, 0);
                    accR[nt] = __builtin_amdgcn_mfma_f32_16x16x32_bf16(Gl8, Rh[nt], accR[nt], 0, 0, 0);
                }
                #pragma unroll
                for (int nt = 0; nt < 2; ++nt)
                    #pragma unroll
                    for (int r = 0; r < 4; ++r) {
                        const int ml  = 4 * o + r;
                        const int joE = tt * 16 + ml;
                        const int jres = imin(2 * joE + 1, nIn - 1);
                        const int n = nl + 16 * nt;
                        const float resv = bf16f(Hih[jres * 40 + n]) + bf16f(Hil[jres * 40 + n]);
                        const float hv = accR[nt][r] + rbv[nt] + resv;
                        const ushort hh = bf16hi(hv);
                        Hoh[joE * 40 + n] = hh;
                        Hol[joE * 40 + n] = bf16hi(hv - bf16f(hh));
                    }
            }
        }
        __syncthreads();
    }

    // ---- skip sum + head (per batch)
    if (tid < 32) {
        const int c = tid;
        float acc = 0.f;
        #pragma unroll
        for (int l2 = 0; l2 < 12; ++l2) {
            float a = sb[l2 * 32 + c];
            #pragma unroll
            for (int ic = 0; ic < 32; ++ic) {
                const float gv = (l2 < 6) ? gTL[((size_t)l2 * BATCH + b) * 32 + ic]
                                          : gcap[l2 - 6][ic];
                a += sw[l2 * 1024 + c * 32 + ic] * gv;
            }
            acc += a;
        }
        ss[c] = fmaxf(acc, 0.f);
    }
    __syncthreads();
    if (tid < 32) {
        float z = f1b[tid];
        #pragma unroll
        for (int ic = 0; ic < 32; ++ic) z += f1w[tid * 32 + ic] * ss[ic];
        z1[tid] = fmaxf(z, 0.f);
    }
    __syncthreads();
    if (tid == 0) {
        float o2 = f2b[0];
        #pragma unroll
        for (int ic = 0; ic < 32; ++ic) o2 += f2w[ic] * z1[ic];
        out[b] = o2;
    }
}

// ---------------------------------------------------------------- launch
extern "C" void kernel_launch(void* const* d_in, const int* in_sizes, int n_in,
                              void* d_out, int out_size, void* d_ws, size_t ws_size,
                              hipStream_t stream)
{
    const float* x      = (const float*)d_in[0];
    const float* in_w   = (const float*)d_in[1];
    const float* in_b   = (const float*)d_in[2];
    const float* dil_w  = (const float*)d_in[3];
    const float* dil_b  = (const float*)d_in[4];
    const float* skip_w = (const float*)d_in[5];
    const float* skip_b = (const float*)d_in[6];
    const float* res_w  = (const float*)d_in[7];
    const float* res_b  = (const float*)d_in[8];
    const float* f1_w   = (const float*)d_in[9];
    const float* f1_b   = (const float*)d_in[10];
    const float* f2_w   = (const float*)d_in[11];
    const float* f2_b   = (const float*)d_in[12];

    char* p = (char*)d_ws;
    ushort* wdh = (ushort*)p; p += 12 * 4096 * 2;
    ushort* wdl = (ushort*)p; p += 12 * 4096 * 2;
    ushort* wrh = (ushort*)p; p += 12 * 1024 * 2;
    ushort* wrl = (ushort*)p; p += 12 * 1024 * 2;
    ushort* c6h = (ushort*)p; p += 32 * 64 * 32 * 2;
    ushort* c6l = (ushort*)p; p += 32 * 64 * 32 * 2;
    float*  gTL = (float*)p;                 // [12][32][32]

    wn_prep<<<dim3((12 * 4096 + 12 * 1024 + 255) / 256), dim3(256), 0, stream>>>(
        dil_w, res_w, wdh, wdl, wrh, wrl);

    wn_fuseA<<<dim3(32, BATCH), dim3(256), 0, stream>>>(
        x, in_w, in_b, wdh, wdl, wrh, wrl, dil_b, res_b, c6h, c6l, gTL);

    wn_fuseB<<<dim3(BATCH), dim3(256), 0, stream>>>(
        c6h, c6l, wdh, wdl, wrh, wrl, dil_b, res_b, gTL,
        skip_w, skip_b, f1_w, f1_b, f2_w, f2_b, (float*)d_out);
}